// Round 10
// baseline (175.240 us; speedup 1.0000x reference)
//
#include <hip/hip_runtime.h>
#include <hip/hip_bf16.h>

#define L_SEQ    1024
#define IN_DIM   256
#define DIM_MSA  32
#define PAIR_DIM 64

typedef float f4 __attribute__((ext_vector_type(4)));
typedef short s8 __attribute__((ext_vector_type(8)));

__device__ __forceinline__ unsigned short f2bf(float f) {
    unsigned u = __float_as_uint(f);
    u = (u + 0x7FFFu + ((u >> 16) & 1u)) >> 16;   // RNE
    return (unsigned short)u;
}

// s[i][c] = b1[c] + sum_d seq[i][d] * W1[c][d]  (fp32 + bf16 copies)
__global__ void k_proj1(const float* __restrict__ seq, const float* __restrict__ W1,
                        const float* __restrict__ b1, float* __restrict__ s,
                        unsigned short* __restrict__ s_bf) {
    int t = blockIdx.x * blockDim.x + threadIdx.x;   // 1024*32 threads
    int i = t >> 5, c = t & 31;
    const float4* sq = (const float4*)(seq + i * IN_DIM);
    const float4* w  = (const float4*)(W1  + c * IN_DIM);
    float a0 = 0.f, a1 = 0.f, a2 = 0.f, a3 = 0.f;
#pragma unroll
    for (int d4 = 0; d4 < IN_DIM / 4; ++d4) {
        float4 x = sq[d4], y = w[d4];
        a0 += x.x * y.x;  a1 += x.y * y.y;
        a2 += x.z * y.z;  a3 += x.w * y.w;
    }
    float v = b1[c] + ((a0 + a1) + (a2 + a3));
    s[t]    = v;
    s_bf[t] = f2bf(v);
}

// tmp_bf[jp][d] = bf16( sum_c s[j][c] * W2[p][c*32+d] ), jp = j*64+p
__global__ void k_proj2(const float* __restrict__ s, const float* __restrict__ W2,
                        unsigned short* __restrict__ tmp_bf) {
    int t = blockIdx.x * blockDim.x + threadIdx.x;   // 1024*64*8 threads
    int q = t & 7, p = (t >> 3) & 63, j = t >> 9;
    const float4* w  = (const float4*)W2;            // idx = p*256 + c*8 + q
    const float*  sj = s + j * DIM_MSA;
    float4 acc = {0.f, 0.f, 0.f, 0.f};
#pragma unroll
    for (int c = 0; c < DIM_MSA; ++c) {
        float  sc = sj[c];
        float4 wv = w[p * 256 + c * 8 + q];
        acc.x += sc * wv.x;  acc.y += sc * wv.y;
        acc.z += sc * wv.z;  acc.w += sc * wv.w;
    }
    ushort4 o;
    o.x = f2bf(acc.x);  o.y = f2bf(acc.y);
    o.z = f2bf(acc.z);  o.w = f2bf(acc.w);
    ((ushort4*)tmp_bf)[t] = o;   // shorts 4t..4t+3 == [jp][d] row-major ✓
}

// out[i][jp] = MFMA( s_bf[i][:], tmp_bf[jp][:] ) + b2[p] + pair[i][jp]
// Block: i-tile (16 i) x j-block (16 j, all p). Wave w: p-quarter w*16..+15,
// walks 16 tiles t (j = jb*16+t). Per tile: 1KB contiguous B load (L2-hot),
// one v_mfma_f32_16x16x32_bf16, 4 pair loads, 4 nt stores.
// A/B both fed with lane(l): element[l&15][k=(l>>4)*8+q] -> k-pairing is
// identity between A and B regardless of HW k-wiring (sum is k-perm-invariant).
// C/D: col=lane&15, row=(lane>>4)*4+reg (m89-verified).
__global__ __launch_bounds__(256) void k_outer_mfma(
    const unsigned short* __restrict__ s_bf, const unsigned short* __restrict__ tmp_bf,
    const float* __restrict__ pair, const float* __restrict__ b2,
    float* __restrict__ out) {
    int tid = threadIdx.x;
    int w = tid >> 6, l = tid & 63;
    int n = l & 15, g = l >> 4;                  // col / k-group
    int it = blockIdx.x >> 6;                    // i-tile 0..63
    int jb = blockIdx.x & 63;                    // j-block 0..63

    // A-frag: s_bf[it*16 + n][g*8 .. g*8+7]
    s8 a = *(const s8*)(s_bf + (size_t)(it * 16 + n) * DIM_MSA + g * 8);
    float bias = b2[w * 16 + n];

    // tile t: jp0 = jb*1024 + t*64 + w*16  (j = jb*16+t, p = w*16..w*16+15)
    const unsigned short* bp = tmp_bf + (size_t)(jb * 1024 + w * 16 + n) * DIM_MSA + g * 8;
    const size_t rs = (size_t)L_SEQ * PAIR_DIM;  // 65536 (i-row stride)
    size_t pbase = (size_t)(it * 16 + g * 4) * rs + (size_t)jb * 1024 + w * 16 + n;
    const float* pp = pair + pbase;
    float*       op = out  + pbase;

    s8 bc = *(const s8*)bp;                      // B for tile 0
    float p0 = pp[0], p1 = pp[rs], p2 = pp[2 * rs], p3 = pp[3 * rs];

#pragma unroll 4
    for (int t = 0; t < 16; ++t) {
        s8 bn = bc; float n0 = 0.f, n1 = 0.f, n2 = 0.f, n3 = 0.f;
        if (t < 15) {                            // prefetch tile t+1
            bn = *(const s8*)(bp + (size_t)(t + 1) * 64 * DIM_MSA);
            const float* pn = pp + (t + 1) * 64;
            n0 = pn[0]; n1 = pn[rs]; n2 = pn[2 * rs]; n3 = pn[3 * rs];
        }
        f4 z = {0.f, 0.f, 0.f, 0.f};
        f4 acc = __builtin_amdgcn_mfma_f32_16x16x32_bf16(a, bc, z, 0, 0, 0);
        float* o = op + t * 64;
        __builtin_nontemporal_store(acc.x + bias + p0, o);
        __builtin_nontemporal_store(acc.y + bias + p1, o + rs);
        __builtin_nontemporal_store(acc.z + bias + p2, o + 2 * rs);
        __builtin_nontemporal_store(acc.w + bias + p3, o + 3 * rs);
        bc = bn; p0 = n0; p1 = n1; p2 = n2; p3 = n3;
    }
}

extern "C" void kernel_launch(void* const* d_in, const int* in_sizes, int n_in,
                              void* d_out, int out_size, void* d_ws, size_t ws_size,
                              hipStream_t stream) {
    const float* seq  = (const float*)d_in[0];   // [1,1024,256]
    const float* pair = (const float*)d_in[1];   // [1,1024,1024,64]
    const float* W1   = (const float*)d_in[2];   // [32,256]
    const float* b1   = (const float*)d_in[3];   // [32]
    const float* W2   = (const float*)d_in[4];   // [64,1024]
    const float* b2   = (const float*)d_in[5];   // [64]
    float* out = (float*)d_out;

    float*          s_ws = (float*)d_ws;                     // 128 KB fp32
    unsigned short* sbf  = (unsigned short*)(s_ws + 32768);  // 64 KB bf16
    unsigned short* tbf  = sbf + 32768;                      // 4 MB bf16 [jp][d]

    k_proj1<<<(L_SEQ * DIM_MSA) / 256, 256, 0, stream>>>(seq, W1, b1, s_ws, sbf);
    k_proj2<<<(L_SEQ * PAIR_DIM * (DIM_MSA / 4)) / 256, 256, 0, stream>>>(s_ws, W2, tbf);
    k_outer_mfma<<<64 * 64, 256, 0, stream>>>(sbf, tbf, pair, b2, out);
}

// Round 11
// 138.792 us; speedup vs baseline: 1.2626x; 1.2626x over previous
//
#include <hip/hip_runtime.h>
#include <hip/hip_bf16.h>

#define L_SEQ    1024
#define IN_DIM   256
#define DIM_MSA  32
#define PAIR_DIM 64
#define ISPLIT   8
#define ICHUNK   (L_SEQ / ISPLIT)   // 128
#define GRP      8                  // prefetch distance (named rotating regs)

// s[i][c] = b1[c] + sum_d seq[i][d] * W1[c][d]
__global__ void k_proj1(const float* __restrict__ seq, const float* __restrict__ W1,
                        const float* __restrict__ b1, float* __restrict__ s) {
    int t = blockIdx.x * blockDim.x + threadIdx.x;   // 1024*32 threads
    int i = t >> 5, c = t & 31;
    const float4* sq = (const float4*)(seq + i * IN_DIM);
    const float4* w  = (const float4*)(W1  + c * IN_DIM);
    float a0 = 0.f, a1 = 0.f, a2 = 0.f, a3 = 0.f;
#pragma unroll
    for (int d4 = 0; d4 < IN_DIM / 4; ++d4) {
        float4 x = sq[d4], y = w[d4];
        a0 += x.x * y.x;  a1 += x.y * y.y;
        a2 += x.z * y.z;  a3 += x.w * y.w;
    }
    s[t] = b1[c] + ((a0 + a1) + (a2 + a3));
}

// tmp[j][p][d] = sum_c s[j][c] * W2[p][c*32+d]   (thread computes 4 consecutive d)
__global__ void k_proj2(const float* __restrict__ s, const float* __restrict__ W2,
                        float* __restrict__ tmp) {
    int t = blockIdx.x * blockDim.x + threadIdx.x;   // 1024*64*8 threads
    int q = t & 7, p = (t >> 3) & 63, j = t >> 9;
    const float4* w  = (const float4*)W2;            // idx = p*256 + c*8 + q
    const float*  sj = s + j * DIM_MSA;
    float4 acc = {0.f, 0.f, 0.f, 0.f};
#pragma unroll
    for (int c = 0; c < DIM_MSA; ++c) {
        float  sc = sj[c];
        float4 wv = w[p * 256 + c * 8 + q];
        acc.x += sc * wv.x;  acc.y += sc * wv.y;
        acc.z += sc * wv.z;  acc.w += sc * wv.w;
    }
    ((float4*)tmp)[t] = acc;   // t = j*512 + p*8 + q  ==  [j][p][d] as float4
}

__device__ __forceinline__ float dot32(const float* __restrict__ srow,
    const float4 r0, const float4 r1, const float4 r2, const float4 r3,
    const float4 r4, const float4 r5, const float4 r6, const float4 r7) {
    const float4* sg = (const float4*)srow;           // wave-uniform -> s_load
    float4 s0 = sg[0], s1 = sg[1], s2 = sg[2], s3 = sg[3],
           s4 = sg[4], s5 = sg[5], s6 = sg[6], s7 = sg[7];
    float a0 = s0.x*r0.x + s0.y*r0.y + s0.z*r0.z + s0.w*r0.w
             + s1.x*r1.x + s1.y*r1.y + s1.z*r1.z + s1.w*r1.w;
    float a1 = s2.x*r2.x + s2.y*r2.y + s2.z*r2.z + s2.w*r2.w
             + s3.x*r3.x + s3.y*r3.y + s3.z*r3.z + s3.w*r3.w;
    float a2 = s4.x*r4.x + s4.y*r4.y + s4.z*r4.z + s4.w*r4.w
             + s5.x*r5.x + s5.y*r5.y + s5.z*r5.z + s5.w*r5.w;
    float a3 = s6.x*r6.x + s6.y*r6.y + s6.z*r6.z + s6.w*r6.w
             + s7.x*r7.x + s7.y*r7.y + s7.z*r7.z + s7.w*r7.w;
    return (a0 + a1) + (a2 + a3);
}

// out[i][j][p] = sum_d s[i][d]*tmp[j][p][d] + b2[p] + pair[i][j][p]
// (byte-identical to R8 — the calibration baseline)
__global__ __launch_bounds__(256) void k_outer(
    const float* __restrict__ s, const float* __restrict__ tmp,
    const float* __restrict__ pair, const float* __restrict__ b2,
    float* __restrict__ out) {
    int tid  = threadIdx.x;
    int wave = tid >> 6, lane = tid & 63;
    int jgrp  = blockIdx.x & 255;               // 256 j-groups of 4
    int chunk = blockIdx.x >> 8;                // ISPLIT i-chunks
    int j  = jgrp * 4 + wave;
    int i0 = chunk * ICHUNK;

    const float4* tj = (const float4*)(tmp + (size_t)(j * PAIR_DIM + lane) * DIM_MSA);
    float4 r0 = tj[0], r1 = tj[1], r2 = tj[2], r3 = tj[3],
           r4 = tj[4], r5 = tj[5], r6 = tj[6], r7 = tj[7];
    float bias = b2[lane];

    const size_t stride = (size_t)L_SEQ * PAIR_DIM;              // 65536
    const float* pr = pair + ((size_t)i0 * L_SEQ + j) * PAIR_DIM + lane;
    float*       po = out  + ((size_t)i0 * L_SEQ + j) * PAIR_DIM + lane;

    float pv0 = pr[0 * stride], pv1 = pr[1 * stride],
          pv2 = pr[2 * stride], pv3 = pr[3 * stride],
          pv4 = pr[4 * stride], pv5 = pr[5 * stride],
          pv6 = pr[6 * stride], pv7 = pr[7 * stride];
    pr += (size_t)GRP * stride;

    int ii = i0;

#define STEP(PV) do {                                                         \
        float dv = dot32(s + (size_t)ii * DIM_MSA, r0,r1,r2,r3,r4,r5,r6,r7);  \
        __builtin_nontemporal_store(dv + bias + (PV), po); po += stride;      \
        (PV) = *pr; pr += stride; ++ii;                                       \
    } while (0)

#define STEPL(PV) do {                                                        \
        float dv = dot32(s + (size_t)ii * DIM_MSA, r0,r1,r2,r3,r4,r5,r6,r7);  \
        __builtin_nontemporal_store(dv + bias + (PV), po); po += stride;      \
        ++ii;                                                                 \
    } while (0)

#pragma unroll 1
    for (int g = 0; g < ICHUNK / GRP - 1; ++g) {
        STEP(pv0); STEP(pv1); STEP(pv2); STEP(pv3);
        STEP(pv4); STEP(pv5); STEP(pv6); STEP(pv7);
    }
    STEPL(pv0); STEPL(pv1); STEPL(pv2); STEPL(pv3);
    STEPL(pv4); STEPL(pv5); STEPL(pv6); STEPL(pv7);

#undef STEP
#undef STEPL
}

// CALIBRATION: known-good streaming pattern (m13-style float4 grid-stride),
// idempotent self-copy out[x] = out[x]. 256 MB read + 256 MB write.
// Measures this harness's achievable mixed r/w HBM BW on these exact buffers.
__global__ __launch_bounds__(256) void k_copy_calib(float4* __restrict__ buf,
                                                    size_t n4) {
    size_t x = (size_t)blockIdx.x * blockDim.x + threadIdx.x;
    size_t step = (size_t)gridDim.x * blockDim.x;
    for (; x < n4; x += step) {
        float4 v = buf[x];
        buf[x] = v;
    }
}

extern "C" void kernel_launch(void* const* d_in, const int* in_sizes, int n_in,
                              void* d_out, int out_size, void* d_ws, size_t ws_size,
                              hipStream_t stream) {
    const float* seq  = (const float*)d_in[0];   // [1,1024,256]
    const float* pair = (const float*)d_in[1];   // [1,1024,1024,64]
    const float* W1   = (const float*)d_in[2];   // [32,256]
    const float* b1   = (const float*)d_in[3];   // [32]
    const float* W2   = (const float*)d_in[4];   // [64,1024]
    const float* b2   = (const float*)d_in[5];   // [64]
    float* out = (float*)d_out;

    float* s_ws   = (float*)d_ws;                         // 1024*32   = 128 KB
    float* tmp_ws = s_ws + (size_t)L_SEQ * DIM_MSA;       // 1024*64*32 = 8 MB

    k_proj1<<<(L_SEQ * DIM_MSA) / 256, 256, 0, stream>>>(seq, W1, b1, s_ws);
    k_proj2<<<(L_SEQ * PAIR_DIM * (DIM_MSA / 4)) / 256, 256, 0, stream>>>(s_ws, W2, tmp_ws);
    k_outer<<<256 * ISPLIT, 256, 0, stream>>>(s_ws, tmp_ws, pair, b2, out);
    k_copy_calib<<<2048, 256, 0, stream>>>((float4*)out,
                                           (size_t)out_size / 4);
}